// Round 4
// baseline (5541.650 us; speedup 1.0000x reference)
//
#include <hip/hip_runtime.h>
#include <stdint.h>

// GTCN2: 10-hop graph conv. Round 4: inputs/outputs are fp32 (R3's NaN proved
// the float tensors are NOT bf16 — fp32 words read as bf16 decode as NaN).
// Internal node-feature storage bf16 (fp32 accum) to keep ws at ~180MB.
// On-device CSR with index filtering (OOB-proof), ws guard.

typedef unsigned short bf16_t;

__device__ __forceinline__ float bf2f(bf16_t u) {
    union { unsigned int i; float f; } v; v.i = ((unsigned int)u) << 16; return v.f;
}
__device__ __forceinline__ bf16_t f2bf(float f) {
    union { float f; unsigned int i; } v; v.f = f;
    unsigned int x = v.i;
    unsigned int r = (x + 0x7fffu + ((x >> 16) & 1u)) >> 16;  // RNE
    return (bf16_t)r;
}

__device__ __forceinline__ void load4f(const float* p, float& a, float& b, float& c, float& d) {
    float4 v = *(const float4*)p; a = v.x; b = v.y; c = v.z; d = v.w;
}
__device__ __forceinline__ void load4f(const bf16_t* p, float& a, float& b, float& c, float& d) {
    ushort4 v = *(const ushort4*)p; a = bf2f(v.x); b = bf2f(v.y); c = bf2f(v.z); d = bf2f(v.w);
}
__device__ __forceinline__ void store4f(float* p, float a, float b, float c, float d) {
    *(float4*)p = make_float4(a, b, c, d);
}
__device__ __forceinline__ void store4f(bf16_t* p, float a, float b, float c, float d) {
    ushort4 u; u.x = f2bf(a); u.y = f2bf(b); u.z = f2bf(c); u.w = f2bf(d);
    *(ushort4*)p = u;
}

__global__ void zero_i32(int* __restrict__ p, int n) {
    int i = blockIdx.x * blockDim.x + threadIdx.x;
    if (i < n) p[i] = 0;
}

// Count edges per row; edges with out-of-range row OR col are dropped entirely
// (same filter as scatter_edges, so CSR stays internally consistent and every
// csr_col entry is provably in [0,N)).
__global__ void count_edges(const int* __restrict__ er, const int* __restrict__ ec,
                            int* __restrict__ cnt, int E, int N) {
    int i = blockIdx.x * blockDim.x + threadIdx.x;
    if (i < E) {
        unsigned r = (unsigned)er[i], c = (unsigned)ec[i];
        if (r < (unsigned)N && c < (unsigned)N) atomicAdd(&cnt[r], 1);
    }
}

// Single-block exclusive scan over row counts -> row_ptr; cnt_cursor rewritten
// in-place to per-row running offsets for the scatter pass.
__global__ __launch_bounds__(1024)
void scan_rows(int* cnt_cursor, int* __restrict__ row_ptr, int n) {
    __shared__ int sums[1024];
    int t = threadIdx.x;
    int chunk = (n + 1023) >> 10;
    int start = t * chunk;
    int end = min(start + chunk, n);
    int s = 0;
    for (int i = start; i < end; ++i) s += cnt_cursor[i];
    sums[t] = s;
    __syncthreads();
    for (int off = 1; off < 1024; off <<= 1) {
        int v = (t >= off) ? sums[t - off] : 0;
        __syncthreads();
        sums[t] += v;
        __syncthreads();
    }
    int run = (t == 0) ? 0 : sums[t - 1];
    for (int i = start; i < end; ++i) {
        int c = cnt_cursor[i];
        row_ptr[i] = run;
        cnt_cursor[i] = run;
        run += c;
    }
    if (t == 1023) row_ptr[n] = sums[1023];
}

__global__ void scatter_edges(const int* __restrict__ er, const int* __restrict__ ec,
                              const float* __restrict__ ev, int* __restrict__ cursor,
                              int* __restrict__ csr_col, float* __restrict__ csr_val,
                              int E, int N) {
    int i = blockIdx.x * blockDim.x + threadIdx.x;
    if (i < E) {
        unsigned r = (unsigned)er[i], c = (unsigned)ec[i];
        if (r < (unsigned)N && c < (unsigned)N) {
            int p = atomicAdd(&cursor[r], 1);
            csr_col[p] = (int)c;
            csr_val[p] = ev[i];
        }
    }
}

// s[row,:] = A2[row]*x0[row,:] + sum_e val[e] * h[col[e],:]
// one block per row; 256 threads = 256 features; bf16 h => 512B coalesced gathers.
__global__ __launch_bounds__(256)
void spmm_kernel(const int* __restrict__ row_ptr, const int* __restrict__ csr_col,
                 const float* __restrict__ csr_val, const bf16_t* __restrict__ h,
                 const bf16_t* __restrict__ x0, const float* __restrict__ A2,
                 bf16_t* __restrict__ s) {
    int row = blockIdx.x;
    int f = threadIdx.x;
    int base = row << 8;  // * 256 features
    float acc = A2[row] * bf2f(x0[base + f]);
    int e = row_ptr[row], e1 = row_ptr[row + 1];
    for (; e + 4 <= e1; e += 4) {
        int c0 = csr_col[e], c1 = csr_col[e + 1], c2 = csr_col[e + 2], c3 = csr_col[e + 3];
        float v0 = csr_val[e], v1 = csr_val[e + 1], v2 = csr_val[e + 2], v3 = csr_val[e + 3];
        float h0 = bf2f(h[(c0 << 8) + f]), h1 = bf2f(h[(c1 << 8) + f]);
        float h2 = bf2f(h[(c2 << 8) + f]), h3 = bf2f(h[(c3 << 8) + f]);
        acc += v0 * h0; acc += v1 * h1; acc += v2 * h2; acc += v3 * h3;
    }
    for (; e < e1; ++e) acc += csr_val[e] * bf2f(h[(csr_col[e] << 8) + f]);
    s[base + f] = f2bf(acc);
}

// C[M,N] = epilogue(A[M,K] @ B[K,N]); B/bias fp32 (problem weights), A/C
// templated (fp32 input x / bf16 ws buffers / fp32 final output).
// 64x64 tile, BK=16, 4x4 microtile, fp32 accumulate.
// add_skip: += A[row,col] (requires K==N, used for s + s@W3). do_relu: relu.
template <typename AT, typename CT>
__global__ __launch_bounds__(256)
void gemm_kernel(const AT* __restrict__ A, const float* __restrict__ B,
                 const float* __restrict__ bias, CT* __restrict__ C,
                 int M, int K, int N, int add_skip, int do_relu) {
    __shared__ float As[16][64];
    __shared__ float Bs[16][64];
    int tid = threadIdx.x;
    int bm = blockIdx.x * 64;
    int bn = blockIdx.y * 64;
    int tx = tid & 15, ty = tid >> 4;
    float acc[4][4] = {};

    int am = tid >> 2;            // 0..63 tile row for A load
    int ak = (tid & 3) << 2;      // 0,4,8,12
    int bk = tid >> 4;            // 0..15 tile k for B load
    int bnn = (tid & 15) << 2;    // 0..60
    bool arow_ok = (bm + am) < M;
    const AT* Aload = A + (size_t)(bm + am) * K + ak;
    const float* Bload = B + (size_t)bk * N + bn + bnn;

    for (int k0 = 0; k0 < K; k0 += 16) {
        float a0, a1, a2, a3;
        if (arow_ok) load4f(Aload + k0, a0, a1, a2, a3);
        else { a0 = a1 = a2 = a3 = 0.f; }
        float bv0, bv1, bv2, bv3;
        load4f(Bload + (size_t)k0 * N, bv0, bv1, bv2, bv3);

        __syncthreads();  // previous iteration's compute done
        As[ak + 0][am] = a0; As[ak + 1][am] = a1; As[ak + 2][am] = a2; As[ak + 3][am] = a3;
        Bs[bk][bnn + 0] = bv0; Bs[bk][bnn + 1] = bv1; Bs[bk][bnn + 2] = bv2; Bs[bk][bnn + 3] = bv3;
        __syncthreads();

        #pragma unroll
        for (int k = 0; k < 16; ++k) {
            float4 av = *(const float4*)&As[k][ty << 2];
            float4 bv = *(const float4*)&Bs[k][tx << 2];
            float ar[4] = {av.x, av.y, av.z, av.w};
            float br[4] = {bv.x, bv.y, bv.z, bv.w};
            #pragma unroll
            for (int i = 0; i < 4; ++i)
                #pragma unroll
                for (int j = 0; j < 4; ++j)
                    acc[i][j] += ar[i] * br[j];
        }
    }

    int col = bn + (tx << 2);
    float4 bbv = *(const float4*)(bias + col);
    float bb[4] = {bbv.x, bbv.y, bbv.z, bbv.w};
    #pragma unroll
    for (int i = 0; i < 4; ++i) {
        int row = bm + (ty << 2) + i;
        if (row >= M) continue;
        float s0 = 0.f, s1 = 0.f, s2 = 0.f, s3 = 0.f;
        if (add_skip) load4f(A + (size_t)row * K + col, s0, s1, s2, s3);
        float o[4] = {acc[i][0] + bb[0] + s0, acc[i][1] + bb[1] + s1,
                      acc[i][2] + bb[2] + s2, acc[i][3] + bb[3] + s3};
        if (do_relu) {
            o[0] = fmaxf(o[0], 0.f); o[1] = fmaxf(o[1], 0.f);
            o[2] = fmaxf(o[2], 0.f); o[3] = fmaxf(o[3], 0.f);
        }
        store4f(C + (size_t)row * N + col, o[0], o[1], o[2], o[3]);
    }
}

extern "C" void kernel_launch(void* const* d_in, const int* in_sizes, int n_in,
                              void* d_out, int out_size, void* d_ws, size_t ws_size,
                              hipStream_t stream) {
    const float* x   = (const float*)d_in[0];
    const int* erow  = (const int*)d_in[1];
    const int* ecol  = (const int*)d_in[2];
    const float* ev  = (const float*)d_in[3];
    const float* A2  = (const float*)d_in[4];
    const float* W1  = (const float*)d_in[5];
    const float* b1  = (const float*)d_in[6];
    const float* W3  = (const float*)d_in[7];
    const float* b3  = (const float*)d_in[8];
    const float* W2  = (const float*)d_in[9];
    const float* b2  = (const float*)d_in[10];
    float* out = (float*)d_out;

    const int N   = in_sizes[4];        // 100000 nodes (A2 is [N,1])
    const int E   = in_sizes[1];        // 3200000 edges
    const int NIN = in_sizes[0] / N;    // 512
    const int NH  = in_sizes[6];        // 256
    const int NO  = in_sizes[10];       // 64
    if (NH != 256) return;              // spmm hard-codes <<8 feature stride

    char* ws = (char*)d_ws;
    size_t off = 0;
    auto alloc = [&](size_t bytes) -> void* {
        void* p = ws + off;
        off += (bytes + 255) & ~(size_t)255;
        return p;
    };
    bf16_t* x0     = (bf16_t*)alloc((size_t)N * NH * 2);
    bf16_t* hA     = (bf16_t*)alloc((size_t)N * NH * 2);
    bf16_t* hB     = (bf16_t*)alloc((size_t)N * NH * 2);
    int*   row_ptr = (int*)alloc((size_t)(N + 1) * 4);
    int*   cursor  = (int*)alloc((size_t)N * 4);
    int*   csr_col = (int*)alloc((size_t)E * 4);
    float* csr_val = (float*)alloc((size_t)E * 4);

    // Guard: if ws is too small, bail (output stays zeroed -> visible absmax
    // = max|ref| = 11.125 instead of an OOB container crash).
    if (off > ws_size) return;

    // --- build CSR (per call; ws is re-poisoned every launch) ---
    zero_i32<<<(N + 255) / 256, 256, 0, stream>>>(cursor, N);
    count_edges<<<(E + 255) / 256, 256, 0, stream>>>(erow, ecol, cursor, E, N);
    scan_rows<<<1, 1024, 0, stream>>>(cursor, row_ptr, N);
    scatter_edges<<<(E + 255) / 256, 256, 0, stream>>>(erow, ecol, ev, cursor,
                                                       csr_col, csr_val, E, N);

    // --- x0 = relu(x @ W1 + b1) ---
    dim3 g1((N + 63) / 64, NH / 64);
    gemm_kernel<float, bf16_t><<<g1, 256, 0, stream>>>(x, W1, b1, x0, N, NIN, NH, 0, 1);

    // --- 10 hops: s = A*h + A2.*x0 ; h = relu(s + s@W3 + b3) ---
    const bf16_t* hin = x0;
    for (int hop = 0; hop < 10; ++hop) {
        spmm_kernel<<<N, NH, 0, stream>>>(row_ptr, csr_col, csr_val, hin, x0, A2, hB);
        gemm_kernel<bf16_t, bf16_t><<<g1, 256, 0, stream>>>(hB, W3, b3, hA, N, NH, NH, 1, 1);
        hin = hA;
    }

    // --- out = h @ W2 + b2 (fp32 output) ---
    dim3 g2((N + 63) / 64, NO / 64);
    gemm_kernel<bf16_t, float><<<g2, 256, 0, stream>>>(hA, W2, b2, out, N, NH, NO, 0, 0);
}

// Round 5
// 4003.686 us; speedup vs baseline: 1.3841x; 1.3841x over previous
//
#include <hip/hip_runtime.h>
#include <stdint.h>

// GTCN2 Round 5: bf16 MFMA GEMMs (16x16x32, m97-style 128x128 tile,
// global_load_lds width=16, B pre-transposed to NxK bf16). fp32 accum,
// fused skip+bias+relu epilogue. SpMM / CSR build unchanged from R4 (passing).

typedef unsigned short bf16_t;
typedef __attribute__((ext_vector_type(8))) short bf16x8;
typedef __attribute__((ext_vector_type(4))) float f32x4;

__device__ __forceinline__ float bf2f(bf16_t u) {
    union { unsigned int i; float f; } v; v.i = ((unsigned int)u) << 16; return v.f;
}
__device__ __forceinline__ bf16_t f2bf(float f) {
    union { float f; unsigned int i; } v; v.f = f;
    unsigned int x = v.i;
    unsigned int r = (x + 0x7fffu + ((x >> 16) & 1u)) >> 16;  // RNE
    return (bf16_t)r;
}

__global__ void zero_i32(int* __restrict__ p, int n) {
    int i = blockIdx.x * blockDim.x + threadIdx.x;
    if (i < n) p[i] = 0;
}

// W: KxN fp32 -> Wt: NxK bf16 (so GEMM B-staging == A-staging pattern).
__global__ void transpose_w(const float* __restrict__ W, bf16_t* __restrict__ Wt,
                            int K, int N) {
    int i = blockIdx.x * blockDim.x + threadIdx.x;
    if (i < K * N) {
        int k = i / N, n = i % N;
        Wt[(size_t)n * K + k] = f2bf(W[i]);
    }
}

__global__ void count_edges(const int* __restrict__ er, const int* __restrict__ ec,
                            int* __restrict__ cnt, int E, int N) {
    int i = blockIdx.x * blockDim.x + threadIdx.x;
    if (i < E) {
        unsigned r = (unsigned)er[i], c = (unsigned)ec[i];
        if (r < (unsigned)N && c < (unsigned)N) atomicAdd(&cnt[r], 1);
    }
}

__global__ __launch_bounds__(1024)
void scan_rows(int* cnt_cursor, int* __restrict__ row_ptr, int n) {
    __shared__ int sums[1024];
    int t = threadIdx.x;
    int chunk = (n + 1023) >> 10;
    int start = t * chunk;
    int end = min(start + chunk, n);
    int s = 0;
    for (int i = start; i < end; ++i) s += cnt_cursor[i];
    sums[t] = s;
    __syncthreads();
    for (int off = 1; off < 1024; off <<= 1) {
        int v = (t >= off) ? sums[t - off] : 0;
        __syncthreads();
        sums[t] += v;
        __syncthreads();
    }
    int run = (t == 0) ? 0 : sums[t - 1];
    for (int i = start; i < end; ++i) {
        int c = cnt_cursor[i];
        row_ptr[i] = run;
        cnt_cursor[i] = run;
        run += c;
    }
    if (t == 1023) row_ptr[n] = sums[1023];
}

__global__ void scatter_edges(const int* __restrict__ er, const int* __restrict__ ec,
                              const float* __restrict__ ev, int* __restrict__ cursor,
                              int* __restrict__ csr_col, float* __restrict__ csr_val,
                              int E, int N) {
    int i = blockIdx.x * blockDim.x + threadIdx.x;
    if (i < E) {
        unsigned r = (unsigned)er[i], c = (unsigned)ec[i];
        if (r < (unsigned)N && c < (unsigned)N) {
            int p = atomicAdd(&cursor[r], 1);
            csr_col[p] = (int)c;
            csr_val[p] = ev[i];
        }
    }
}

// s[row,:] = A2[row]*x0[row,:] + sum_e val[e]*h[col[e],:]; bf16 h, 512B gathers.
__global__ __launch_bounds__(256)
void spmm_kernel(const int* __restrict__ row_ptr, const int* __restrict__ csr_col,
                 const float* __restrict__ csr_val, const bf16_t* __restrict__ h,
                 const bf16_t* __restrict__ x0, const float* __restrict__ A2,
                 bf16_t* __restrict__ s) {
    int row = blockIdx.x;
    int f = threadIdx.x;
    int base = row << 8;
    float acc = A2[row] * bf2f(x0[base + f]);
    int e = row_ptr[row], e1 = row_ptr[row + 1];
    for (; e + 4 <= e1; e += 4) {
        int c0 = csr_col[e], c1 = csr_col[e + 1], c2 = csr_col[e + 2], c3 = csr_col[e + 3];
        float v0 = csr_val[e], v1 = csr_val[e + 1], v2 = csr_val[e + 2], v3 = csr_val[e + 3];
        float h0 = bf2f(h[(c0 << 8) + f]), h1 = bf2f(h[(c1 << 8) + f]);
        float h2 = bf2f(h[(c2 << 8) + f]), h3 = bf2f(h[(c3 << 8) + f]);
        acc += v0 * h0; acc += v1 * h1; acc += v2 * h2; acc += v3 * h3;
    }
    for (; e < e1; ++e) acc += csr_val[e] * bf2f(h[(csr_col[e] << 8) + f]);
    s[base + f] = f2bf(acc);
}

// MFMA GEMM: C[M,Nfull] = epi(A[M,K] @ Bt[Nfull,K]^T).
// Tile: (WM*64) x (WN*64), 4 waves, each wave 64x64 via 4x4 of 16x16x32 MFMA.
// BK=32. A bf16 (global_load_lds) or fp32 (convert-in-LDS). Bt bf16 NxK.
// SKIP: C += A[row,col] (requires Nfull<=K, hop skip). RELU on epilogue.
template <int WM, int WN, bool AF32, bool SKIP, bool RELU, typename CT>
__global__ __launch_bounds__(256)
void mfma_gemm(const void* __restrict__ Av, const bf16_t* __restrict__ Bt,
               const float* __restrict__ bias, CT* __restrict__ C,
               int M, int K, int Nfull) {
    constexpr int TM = WM * 64;
    constexpr int TN = WN * 64;
    __shared__ bf16_t As[TM * 32];
    __shared__ bf16_t Bs[TN * 32];
    const int tid = threadIdx.x;
    const int w = tid >> 6, lane = tid & 63;
    const int q = lane >> 4, l16 = lane & 15;
    const int bm = blockIdx.x * TM;
    const int bn = blockIdx.y * TN;
    const int wm = (w % WM) * 64;
    const int wn = (w / WM) * 64;

    f32x4 acc[4][4] = {};

    for (int k0 = 0; k0 < K; k0 += 32) {
        // ---- stage A tile [TM][32] ----
        if constexpr (AF32) {
            // TM must be 128 here: thread t covers row t/2, 16 elements.
            const float* A = (const float*)Av;
            int row = tid >> 1;
            int gr = min(bm + row, M - 1);
            const float* src = A + (size_t)gr * K + k0 + (tid & 1) * 16;
            bf16_t* dst = As + row * 32 + (tid & 1) * 16;
            #pragma unroll
            for (int g = 0; g < 4; ++g) {
                float4 v = *(const float4*)(src + 4 * g);
                ushort4 u;
                u.x = f2bf(v.x); u.y = f2bf(v.y); u.z = f2bf(v.z); u.w = f2bf(v.w);
                *(ushort4*)(dst + 4 * g) = u;
            }
        } else {
            const bf16_t* A = (const bf16_t*)Av;
            #pragma unroll
            for (int r = 0; r < TM / 64; ++r) {
                int rowbase = r * 64 + w * 16;           // wave-uniform
                int row = rowbase + (lane >> 2);
                int gr = min(bm + row, M - 1);           // clamp tail rows
                const bf16_t* gp = A + (size_t)gr * K + k0 + (lane & 3) * 8;
                bf16_t* lp = As + rowbase * 32 + lane * 8; // contiguous lane order
                __builtin_amdgcn_global_load_lds(
                    (const __attribute__((address_space(1))) unsigned int*)gp,
                    (__attribute__((address_space(3))) unsigned int*)lp, 16, 0, 0);
            }
        }
        // ---- stage B tile [TN][32] from Bt (NxK row-major) ----
        #pragma unroll
        for (int r = 0; r < TN / 64; ++r) {
            int rowbase = r * 64 + w * 16;
            int row = rowbase + (lane >> 2);
            const bf16_t* gp = Bt + (size_t)(bn + row) * K + k0 + (lane & 3) * 8;
            bf16_t* lp = Bs + rowbase * 32 + lane * 8;
            __builtin_amdgcn_global_load_lds(
                (const __attribute__((address_space(1))) unsigned int*)gp,
                (__attribute__((address_space(3))) unsigned int*)lp, 16, 0, 0);
        }
        __syncthreads();  // drains vmcnt (global_load_lds) + lgkm, then barrier

        bf16x8 afr[4], bfr[4];
        #pragma unroll
        for (int ms = 0; ms < 4; ++ms)
            afr[ms] = *(const bf16x8*)&As[(wm + ms * 16 + l16) * 32 + q * 8];
        #pragma unroll
        for (int ns = 0; ns < 4; ++ns)
            bfr[ns] = *(const bf16x8*)&Bs[(wn + ns * 16 + l16) * 32 + q * 8];
        #pragma unroll
        for (int ms = 0; ms < 4; ++ms)
            #pragma unroll
            for (int ns = 0; ns < 4; ++ns)
                acc[ms][ns] = __builtin_amdgcn_mfma_f32_16x16x32_bf16(
                    afr[ms], bfr[ns], acc[ms][ns], 0, 0, 0);
        __syncthreads();  // LDS consumed; safe to overwrite next iter
    }

    // ---- epilogue: C/D layout col=lane&15, row=quad*4+reg ----
    const bf16_t* Askip = (const bf16_t*)Av;  // used only when SKIP (bf16 A)
    #pragma unroll
    for (int ms = 0; ms < 4; ++ms) {
        #pragma unroll
        for (int r = 0; r < 4; ++r) {
            int row = bm + wm + ms * 16 + q * 4 + r;
            if (row < M) {
                #pragma unroll
                for (int ns = 0; ns < 4; ++ns) {
                    int col = bn + wn + ns * 16 + l16;
                    float v = acc[ms][ns][r] + bias[col];
                    if constexpr (SKIP) v += bf2f(Askip[(size_t)row * K + col]);
                    if constexpr (RELU) v = fmaxf(v, 0.f);
                    if constexpr (sizeof(CT) == 2) C[(size_t)row * Nfull + col] = (CT)f2bf(v);
                    else                           C[(size_t)row * Nfull + col] = (CT)v;
                }
            }
        }
    }
}

extern "C" void kernel_launch(void* const* d_in, const int* in_sizes, int n_in,
                              void* d_out, int out_size, void* d_ws, size_t ws_size,
                              hipStream_t stream) {
    const float* x   = (const float*)d_in[0];
    const int* erow  = (const int*)d_in[1];
    const int* ecol  = (const int*)d_in[2];
    const float* ev  = (const float*)d_in[3];
    const float* A2  = (const float*)d_in[4];
    const float* W1  = (const float*)d_in[5];
    const float* b1  = (const float*)d_in[6];
    const float* W3  = (const float*)d_in[7];
    const float* b3  = (const float*)d_in[8];
    const float* W2  = (const float*)d_in[9];
    const float* b2  = (const float*)d_in[10];
    float* out = (float*)d_out;

    const int N   = in_sizes[4];        // 100000 nodes
    const int E   = in_sizes[1];        // 3200000 edges
    const int NIN = in_sizes[0] / N;    // 512
    const int NH  = in_sizes[6];        // 256
    const int NO  = in_sizes[10];       // 64
    if (NH != 256 || NIN != 512 || NO != 64) return;  // layout hard-coded

    char* ws = (char*)d_ws;
    size_t off = 0;
    auto alloc = [&](size_t bytes) -> void* {
        void* p = ws + off;
        off += (bytes + 255) & ~(size_t)255;
        return p;
    };
    bf16_t* x0     = (bf16_t*)alloc((size_t)N * NH * 2);
    bf16_t* hA     = (bf16_t*)alloc((size_t)N * NH * 2);
    bf16_t* hB     = (bf16_t*)alloc((size_t)N * NH * 2);
    int*   row_ptr = (int*)alloc((size_t)(N + 1) * 4);
    int*   cursor  = (int*)alloc((size_t)N * 4);
    int*   csr_col = (int*)alloc((size_t)E * 4);
    float* csr_val = (float*)alloc((size_t)E * 4);
    bf16_t* W1t    = (bf16_t*)alloc((size_t)NIN * NH * 2);  // [256][512]
    bf16_t* W3t    = (bf16_t*)alloc((size_t)NH * NH * 2);   // [256][256]
    bf16_t* W2t    = (bf16_t*)alloc((size_t)NH * NO * 2);   // [64][256]
    if (off > ws_size) return;  // visible absmax failure, not an OOB crash

    // --- build CSR + transposed bf16 weights ---
    zero_i32<<<(N + 255) / 256, 256, 0, stream>>>(cursor, N);
    count_edges<<<(E + 255) / 256, 256, 0, stream>>>(erow, ecol, cursor, E, N);
    scan_rows<<<1, 1024, 0, stream>>>(cursor, row_ptr, N);
    scatter_edges<<<(E + 255) / 256, 256, 0, stream>>>(erow, ecol, ev, cursor,
                                                       csr_col, csr_val, E, N);
    transpose_w<<<(NIN * NH + 255) / 256, 256, 0, stream>>>(W1, W1t, NIN, NH);
    transpose_w<<<(NH * NH + 255) / 256, 256, 0, stream>>>(W3, W3t, NH, NH);
    transpose_w<<<(NH * NO + 255) / 256, 256, 0, stream>>>(W2, W2t, NH, NO);

    // --- x0 = relu(x @ W1 + b1): fp32 A, 128x128 tile ---
    dim3 g1((N + 127) / 128, NH / 128);
    mfma_gemm<2, 2, true, false, true, bf16_t><<<g1, 256, 0, stream>>>(
        x, W1t, b1, x0, N, NIN, NH);

    // --- 10 hops ---
    const bf16_t* hin = x0;
    for (int hop = 0; hop < 10; ++hop) {
        spmm_kernel<<<N, NH, 0, stream>>>(row_ptr, csr_col, csr_val, hin, x0, A2, hB);
        mfma_gemm<2, 2, false, true, true, bf16_t><<<g1, 256, 0, stream>>>(
            hB, W3t, b3, hA, N, NH, NH);
        hin = hA;
    }

    // --- out = h @ W2 + b2: 256x64 tile (N=64) ---
    dim3 g2((N + 255) / 256, 1);
    mfma_gemm<4, 1, false, false, false, float><<<g2, 256, 0, stream>>>(
        hA, W2t, b2, out, N, NH, NO);
}